// Round 5
// baseline (589.982 us; speedup 1.0000x reference)
//
#include <hip/hip_runtime.h>
#include <math.h>

#define BATCH   64
#define DIMC    384
#define KEY_DIM 16
#define HEADS   8
#define DD      64
#define DH      512
#define NH_KD   128
#define RES     28
#define RES2    14
#define NN      784
#define NN2     196
#define OUT_DIM 384
#define SCALE   0.25f
#define XPAD    896     // 7*128
#define QPAD    256     // 2*128

typedef __attribute__((ext_vector_type(8))) short bf16x8;
typedef __attribute__((ext_vector_type(4))) float f32x4;

#define MFMA32(a, b, c) __builtin_amdgcn_mfma_f32_16x16x32_bf16(a, b, c, 0, 0, 0)

__device__ inline short f2bf(float f) {
    unsigned u = __float_as_uint(f);
    unsigned r = (u + 0x7fff + ((u >> 16) & 1)) >> 16;
    return (short)r;
}
__device__ inline float bf2f(short h) {
    return __uint_as_float(((unsigned)(unsigned short)h) << 16);
}

// ws byte offsets
#define O_QIN      0u
#define O_QINT_HI  20971520u
#define O_QINT_LO  33554432u
#define O_XT_HI    0u
#define O_XT_LO    44040192u
#define O_VLOCAL   0u
#define O_ATTNT    25690112u
#define O_GT_HI    51380224u
#define O_GT_LO    68157440u
#define O_Q_HI     88080384u
#define O_Q_LO     91291648u
#define O_K_HI     94502912u
#define O_K_LO     107347968u
#define O_V_HI     120193024u
#define O_V_LO     171573248u
#define O_BIASM    222953472u
#define O_W_HI     227870720u
#define O_W_LO     228853760u

// ---------------- qin = dwconv3x3 s2 (pad 1) + pool ----------------
__global__ void qin_kernel(const float* __restrict__ x, const float* __restrict__ ql_w,
                           const float* __restrict__ ql_b, float* __restrict__ qin) {
    int c = blockIdx.x, b = blockIdx.y, n2 = threadIdx.x;
    if (n2 >= NN2) return;
    int i = n2 / RES2, j = n2 % RES2;
    const float* xp = x + ((size_t)b * DIMC + c) * (RES * RES);
    const float* w  = ql_w + c * 9;
    float acc = ql_b[c];
    #pragma unroll
    for (int di = 0; di < 3; ++di) {
        int r = 2 * i + di - 1;
        if (r < 0 || r >= RES) continue;
        #pragma unroll
        for (int dj = 0; dj < 3; ++dj) {
            int cc = 2 * j + dj - 1;
            if (cc < 0 || cc >= RES) continue;
            acc += xp[r * RES + cc] * w[di * 3 + dj];
        }
    }
    acc += xp[(2 * i) * RES + 2 * j];
    qin[((size_t)b * DIMC + c) * NN2 + n2] = acc;
}

// ---------------- weight split ----------------
__global__ void wsplit_kernel(const float* __restrict__ w0, const float* __restrict__ w1,
                              const float* __restrict__ w2, const float* __restrict__ w3,
                              short* __restrict__ hi, short* __restrict__ lo) {
    int i = blockIdx.x * 256 + threadIdx.x;
    if (i >= 491520) return;
    const float* src; int j = i;
    if (j < 49152) src = w0;
    else if (j < 98304) { src = w1; j -= 49152; }
    else if (j < 294912) { src = w2; j -= 98304; }
    else { src = w3; j -= 294912; }
    float v = src[j];
    short h = f2bf(v);
    hi[i] = h;
    lo[i] = f2bf(v - bf2f(h));
}

// ---------------- transpose + split ----------------
__global__ void tsplit_kernel(const float* __restrict__ in, short* __restrict__ out_hi,
                              short* __restrict__ out_lo, int C, int N, int Npad) {
    __shared__ float tile[32][33];
    int ntb = blockIdx.x * 32, ctb = blockIdx.y * 32, b = blockIdx.z;
    int tn = threadIdx.x & 31, tc4 = threadIdx.x >> 5;
    #pragma unroll
    for (int i = 0; i < 4; ++i) {
        int c = tc4 + i * 8;
        int n = ntb + tn;
        tile[c][tn] = (n < N) ? in[((size_t)b * C + ctb + c) * N + n] : 0.f;
    }
    __syncthreads();
    int tc = threadIdx.x & 31, tn4 = threadIdx.x >> 5;
    #pragma unroll
    for (int i = 0; i < 4; ++i) {
        int n = tn4 + i * 8;
        float v = tile[tc][n];
        short h = f2bf(v);
        size_t o = ((size_t)b * Npad + ntb + n) * C + ctb + tc;
        out_hi[o] = h;
        out_lo[o] = f2bf(v - bf2f(h));
    }
}

// ---------------- split-bf16 MFMA GEMM ----------------
__global__ __launch_bounds__(256)
void gemm_split_kernel(const short* __restrict__ Ag_hi, const short* __restrict__ Ag_lo,
                       const short* __restrict__ Bg_hi, const short* __restrict__ Bg_lo,
                       const float* __restrict__ bias, const float* __restrict__ s,
                       const float* __restrict__ off,
                       float* __restrict__ out_f, short* __restrict__ out_hi,
                       short* __restrict__ out_lo, int mode,
                       int C, int Nn, int Npad) {
    __shared__ __align__(16) short Ah[128 * 32], Al[128 * 32], Bh[128 * 32], Bl[128 * 32];

    const int t = threadIdx.x;
    const int n0 = blockIdx.x * 128, o0 = blockIdx.y * 128, b = blockIdx.z;
    const int O = gridDim.y * 128;
    const int lane = t & 63, wid = t >> 6;
    const int wm = wid & 1, wn = wid >> 1;
    const int lr = lane & 15, kg = lane >> 4;

    f32x4 acc[4][4];
    #pragma unroll
    for (int m = 0; m < 4; ++m)
        #pragma unroll
        for (int n = 0; n < 4; ++n)
            acc[m][n] = (f32x4){0.f, 0.f, 0.f, 0.f};

    const int srow = t >> 2;
    const int sch  = (t & 3) * 8;
    const size_t aBase = (size_t)(o0 + srow) * C + sch;
    const size_t bBase = ((size_t)b * Npad + n0 + srow) * C + sch;
    const size_t rstep = (size_t)64 * C;

    bf16x8 rA[2], rAl[2], rB[2], rBl[2];
    #pragma unroll
    for (int p = 0; p < 2; ++p) {
        rA[p]  = *(const bf16x8*)(Ag_hi + aBase + p * rstep);
        rAl[p] = *(const bf16x8*)(Ag_lo + aBase + p * rstep);
        rB[p]  = *(const bf16x8*)(Bg_hi + bBase + p * rstep);
        rBl[p] = *(const bf16x8*)(Bg_lo + bBase + p * rstep);
    }

    for (int k0 = 0;; k0 += 32) {
        #pragma unroll
        for (int p = 0; p < 2; ++p) {
            int la = (srow + p * 64) * 32 + sch;
            *(bf16x8*)&Ah[la] = rA[p];
            *(bf16x8*)&Al[la] = rAl[p];
            *(bf16x8*)&Bh[la] = rB[p];
            *(bf16x8*)&Bl[la] = rBl[p];
        }
        __syncthreads();

        if (k0 + 32 < C) {
            #pragma unroll
            for (int p = 0; p < 2; ++p) {
                rA[p]  = *(const bf16x8*)(Ag_hi + aBase + (k0 + 32) + p * rstep);
                rAl[p] = *(const bf16x8*)(Ag_lo + aBase + (k0 + 32) + p * rstep);
                rB[p]  = *(const bf16x8*)(Bg_hi + bBase + (k0 + 32) + p * rstep);
                rBl[p] = *(const bf16x8*)(Bg_lo + bBase + (k0 + 32) + p * rstep);
            }
        }

        bf16x8 ah[4], al[4];
        #pragma unroll
        for (int m = 0; m < 4; ++m) {
            int row = wm * 64 + m * 16 + lr;
            ah[m] = *(const bf16x8*)&Ah[row * 32 + kg * 8];
            al[m] = *(const bf16x8*)&Al[row * 32 + kg * 8];
        }
        #pragma unroll
        for (int nf = 0; nf < 4; ++nf) {
            int row = wn * 64 + nf * 16 + lr;
            bf16x8 bh = *(const bf16x8*)&Bh[row * 32 + kg * 8];
            bf16x8 bl = *(const bf16x8*)&Bl[row * 32 + kg * 8];
            #pragma unroll
            for (int m = 0; m < 4; ++m) {
                acc[m][nf] = MFMA32(ah[m], bh, acc[m][nf]);
                acc[m][nf] = MFMA32(ah[m], bl, acc[m][nf]);
                acc[m][nf] = MFMA32(al[m], bh, acc[m][nf]);
            }
        }
        if (k0 + 32 >= C) break;
        __syncthreads();
    }

    #pragma unroll
    for (int m = 0; m < 4; ++m) {
        #pragma unroll
        for (int nf = 0; nf < 4; ++nf) {
            int col = n0 + wn * 64 + nf * 16 + lr;
            if (col >= Nn) continue;
            #pragma unroll
            for (int r = 0; r < 4; ++r) {
                int row = o0 + wm * 64 + m * 16 + kg * 4 + r;
                float a = s[row];
                float v = acc[m][nf][r] * a + (bias[row] * a + off[row]);
                size_t oidx = ((size_t)b * O + row) * Nn + col;
                if (mode == 0) {
                    out_f[oidx] = v;
                } else {
                    short h = f2bf(v);
                    out_hi[oidx] = h;
                    out_lo[oidx] = f2bf(v - bf2f(h));
                }
            }
        }
    }
}

// ---------------- v_local ----------------
__global__ void vlocal_kernel(const short* __restrict__ vh, const short* __restrict__ vl,
                              const float* __restrict__ vl_w, const float* __restrict__ vl_b,
                              const float* __restrict__ vl_s, const float* __restrict__ vl_o,
                              float* __restrict__ vlocal) {
    int c = blockIdx.x, b = blockIdx.y, n2 = threadIdx.x;
    if (n2 >= NN2) return;
    int i = n2 / RES2, j = n2 % RES2;
    const size_t base = ((size_t)b * DH + c) * NN;
    const float* w = vl_w + c * 9;
    float acc = vl_b[c];
    #pragma unroll
    for (int di = 0; di < 3; ++di) {
        int r = 2 * i + di - 1;
        if (r < 0 || r >= RES) continue;
        #pragma unroll
        for (int dj = 0; dj < 3; ++dj) {
            int cc = 2 * j + dj - 1;
            if (cc < 0 || cc >= RES) continue;
            size_t idx = base + r * RES + cc;
            acc += (bf2f(vh[idx]) + bf2f(vl[idx])) * w[di * 3 + dj];
        }
    }
    vlocal[((size_t)b * DH + c) * NN2 + n2] = acc * vl_s[c] + vl_o[c];
}

// ---------------- bias expand ----------------
__global__ void bias_expand_kernel(const float* __restrict__ ab, const int* __restrict__ bidx,
                                   float* __restrict__ biasM, int n_off) {
    int i = blockIdx.x * 256 + threadIdx.x;
    int h = blockIdx.y;
    if (i >= NN2 * NN) return;
    biasM[(size_t)h * NN2 * NN + i] = ab[h * n_off + bidx[i]];
}

// ---------------- MFMA attention, swizzled LDS + prefetch pipeline + XCD remap ----------------
__global__ __launch_bounds__(256, 3)
void attn_mfma3_kernel(const short* __restrict__ qh, const short* __restrict__ ql,
                       const short* __restrict__ kh, const short* __restrict__ kl,
                       const short* __restrict__ vh, const short* __restrict__ vl,
                       const float* __restrict__ biasM, float* __restrict__ outT) {
    __shared__ __align__(16) short Qh[64][32], Ql[64][32];
    __shared__ __align__(16) char  KhB[64 * 64], KlB[64 * 64];     // [key][c] swizzled, 64B rows
    __shared__ __align__(16) char  VhB[64 * 128], VlB[64 * 128];   // [d][key] swizzled, 128B rows
    __shared__ __align__(16) short Ps[4][16 * 64];

    const int t = threadIdx.x;
    // XCD-aware remap: 8 heads <-> 8 XCDs (round-robin dispatch); qt innermost for K/V L2 reuse
    const int bid = blockIdx.x;
    const int h   = bid & 7;
    const int idx = bid >> 3;
    const int qt  = idx & 3;
    const int b   = idx >> 2;

    const int lane = t & 63, wid = t >> 6;
    const int lr = lane & 15, kg = lane >> 4;
    const int qg = qt * 64 + wid * 16 + lr;

    {   // zero-init Q (pad cols) and K (pad slots)
        int* z;
        z = (int*)&Qh[0][0]; for (int i = t; i < 1024; i += 256) z[i] = 0;
        z = (int*)&Ql[0][0]; for (int i = t; i < 1024; i += 256) z[i] = 0;
        z = (int*)KhB;       for (int i = t; i < 1024; i += 256) z[i] = 0;
        z = (int*)KlB;       for (int i = t; i < 1024; i += 256) z[i] = 0;
    }
    __syncthreads();

    {   // stage Q [64 q][16 c]
        int c = t >> 4, q4 = (t & 15) * 4;
        size_t base = ((size_t)(b * NH_KD + h * KEY_DIM + c)) * NN2 + qt * 64 + q4;
        short4 hv = {0, 0, 0, 0}, lv = {0, 0, 0, 0};
        if (qt * 64 + q4 + 3 < NN2) {
            hv = *(const short4*)(qh + base);
            lv = *(const short4*)(ql + base);
        }
        #pragma unroll
        for (int j = 0; j < 4; ++j) {
            Qh[q4 + j][c] = ((const short*)&hv)[j];
            Ql[q4 + j][c] = ((const short*)&lv)[j];
        }
    }

    // staging coords
    const int kc   = t >> 4;          // c for K, d0 for V
    const int key4 = (t & 15) * 4;
    const size_t kgbase = ((size_t)(b * NH_KD + h * KEY_DIM + kc)) * NN + key4;
    const size_t vgbase = ((size_t)(b * DH + h * DD + kc)) * NN + key4;
    const float* bbp = biasM + ((size_t)h * NN2 + (qg < NN2 ? qg : 0)) * NN;

    short4 pKh, pKl, pVh[4], pVl[4];
    float4 pB[4];
    const short4 z4 = {0, 0, 0, 0};

    auto PREFETCH = [&](int tile) {
        int k0 = tile * 64;
        bool ok = (k0 + key4 + 3) < NN;
        pKh = ok ? *(const short4*)(kh + kgbase + k0) : z4;
        pKl = ok ? *(const short4*)(kl + kgbase + k0) : z4;
        #pragma unroll
        for (int i = 0; i < 4; ++i) {
            pVh[i] = ok ? *(const short4*)(vh + vgbase + (size_t)i * 16 * NN + k0) : z4;
            pVl[i] = ok ? *(const short4*)(vl + vgbase + (size_t)i * 16 * NN + k0) : z4;
        }
        #pragma unroll
        for (int nt = 0; nt < 4; ++nt) {
            int keyb = k0 + nt * 16 + kg * 4;
            bool kv = ((keyb + 3) < NN) && (qg < NN2);
            float4 zb = {0.f, 0.f, 0.f, 0.f};
            pB[nt] = kv ? *(const float4*)(bbp + keyb) : zb;
        }
    };
    auto STORE_LDS = [&]() {
        #pragma unroll
        for (int j = 0; j < 4; ++j) {
            int row = key4 + j;
            int off = (kc * 2) ^ ((row & 3) << 4);
            *(short*)(KhB + row * 64 + off) = ((const short*)&pKh)[j];
            *(short*)(KlB + row * 64 + off) = ((const short*)&pKl)[j];
        }
        #pragma unroll
        for (int i = 0; i < 4; ++i) {
            int d = kc + i * 16;
            int off = (key4 * 2) ^ ((d & 7) << 4);
            *(short4*)(VhB + d * 128 + off) = pVh[i];
            *(short4*)(VlB + d * 128 + off) = pVl[i];
        }
    };

    PREFETCH(0);
    STORE_LDS();
    __syncthreads();

    bf16x8 qa_h = *(const bf16x8*)&Qh[wid * 16 + lr][kg * 8];
    bf16x8 qa_l = *(const bf16x8*)&Ql[wid * 16 + lr][kg * 8];

    f32x4 acc[4];
    #pragma unroll
    for (int n = 0; n < 4; ++n) acc[n] = (f32x4){0.f, 0.f, 0.f, 0.f};
    float sacc = 0.f;
    char* Psw = (char*)&Ps[wid][0];

    for (int tile = 0; tile < 13; ++tile) {
        const int k0 = tile * 64;
        float4 cB[4];
        #pragma unroll
        for (int nt = 0; nt < 4; ++nt) cB[nt] = pB[nt];
        if (tile < 12) PREFETCH(tile + 1);

        // QK^T swapped: A=K rows(keys), B=Q cols(q)
        #pragma unroll
        for (int nt = 0; nt < 4; ++nt) {
            int rowa = nt * 16 + lr;
            int koff = (kg * 16) ^ ((rowa & 3) << 4);
            bf16x8 ka_h = *(const bf16x8*)(KhB + rowa * 64 + koff);
            bf16x8 ka_l = *(const bf16x8*)(KlB + rowa * 64 + koff);
            f32x4 sc = (f32x4){0.f, 0.f, 0.f, 0.f};
            sc = MFMA32(ka_h, qa_h, sc);
            sc = MFMA32(ka_h, qa_l, sc);
            sc = MFMA32(ka_l, qa_h, sc);

            int keyb = k0 + nt * 16 + kg * 4;
            bool kvalid = (keyb + 3) < NN;
            short4 pk;
            #pragma unroll
            for (int r = 0; r < 4; ++r) {
                float sv = sc[r] * SCALE + ((const float*)&cB[nt])[r];
                float pv = kvalid ? __expf(sv) : 0.f;
                sacc += pv;
                ((short*)&pk)[r] = f2bf(pv);
            }
            *(short4*)(Psw + lr * 128 + ((nt * 32 + kg * 8) ^ ((lr & 7) << 4))) = pk;
        }

        // PV
        #pragma unroll
        for (int ks = 0; ks < 2; ++ks) {
            bf16x8 pa = *(const bf16x8*)(Psw + lr * 128 + ((ks * 64 + kg * 16) ^ ((lr & 7) << 4)));
            #pragma unroll
            for (int nt = 0; nt < 4; ++nt) {
                int rowv = nt * 16 + lr;
                int voff = (ks * 64 + kg * 16) ^ ((rowv & 7) << 4);
                bf16x8 vfh = *(const bf16x8*)(VhB + rowv * 128 + voff);
                bf16x8 vfl = *(const bf16x8*)(VlB + rowv * 128 + voff);
                acc[nt] = MFMA32(pa, vfh, acc[nt]);
                acc[nt] = MFMA32(pa, vfl, acc[nt]);
            }
        }

        if (tile < 12) {
            __syncthreads();
            STORE_LDS();
            __syncthreads();
        }
    }

    sacc += __shfl_xor(sacc, 16, 64);
    sacc += __shfl_xor(sacc, 32, 64);

    #pragma unroll
    for (int r = 0; r < 4; ++r) {
        int qrow = qt * 64 + wid * 16 + kg * 4 + r;
        if (qrow >= NN2) continue;
        float inv = 1.f / __shfl(sacc, kg * 4 + r, 64);
        #pragma unroll
        for (int nt = 0; nt < 4; ++nt) {
            int d = nt * 16 + lr;
            outT[((size_t)b * NN2 + qrow) * DH + h * DD + d] = acc[nt][r] * inv;
        }
    }
}

// ---------------- gelu(attnT + vlocal^T) -> gT hi/lo ----------------
__global__ void gelu_addT_kernel(const float* __restrict__ aT, const float* __restrict__ vloc,
                                 short* __restrict__ g_hi, short* __restrict__ g_lo) {
    __shared__ float tile[32][33];
    int ntb = blockIdx.x * 32, ctb = blockIdx.y * 32, b = blockIdx.z;
    int tn = threadIdx.x & 31, tc4 = threadIdx.x >> 5;
    #pragma unroll
    for (int i = 0; i < 4; ++i) {
        int c = tc4 + i * 8;
        int n = ntb + tn;
        tile[c][tn] = (n < NN2) ? vloc[((size_t)b * DH + ctb + c) * NN2 + n] : 0.f;
    }
    __syncthreads();
    int tc = threadIdx.x & 31, tn4 = threadIdx.x >> 5;
    #pragma unroll
    for (int i = 0; i < 4; ++i) {
        int n = ntb + tn4 + i * 8;
        float g = 0.f;
        if (n < NN2) {
            float sum = aT[((size_t)b * NN2 + n) * DH + ctb + tc] + tile[tc][tn4 + i * 8];
            g = 0.5f * sum * (1.f + erff(sum * 0.70710678118654752440f));
        }
        short hh = f2bf(g);
        size_t o = ((size_t)b * QPAD + n) * DH + ctb + tc;
        g_hi[o] = hh;
        g_lo[o] = f2bf(g - bf2f(hh));
    }
}

extern "C" void kernel_launch(void* const* d_in, const int* in_sizes, int n_in,
                              void* d_out, int out_size, void* d_ws, size_t ws_size,
                              hipStream_t stream) {
    const float* x     = (const float*)d_in[0];
    const float* ql_w  = (const float*)d_in[1];
    const float* ql_b  = (const float*)d_in[2];
    const float* qp_w  = (const float*)d_in[3];
    const float* qp_b  = (const float*)d_in[4];
    const float* qp_s  = (const float*)d_in[5];
    const float* qp_o  = (const float*)d_in[6];
    const float* k_w   = (const float*)d_in[7];
    const float* k_b   = (const float*)d_in[8];
    const float* k_s   = (const float*)d_in[9];
    const float* k_o   = (const float*)d_in[10];
    const float* v_w   = (const float*)d_in[11];
    const float* v_b   = (const float*)d_in[12];
    const float* v_s   = (const float*)d_in[13];
    const float* v_o   = (const float*)d_in[14];
    const float* vl_w  = (const float*)d_in[15];
    const float* vl_b  = (const float*)d_in[16];
    const float* vl_s  = (const float*)d_in[17];
    const float* vl_o  = (const float*)d_in[18];
    const float* p_w   = (const float*)d_in[19];
    const float* p_b   = (const float*)d_in[20];
    const float* p_s   = (const float*)d_in[21];
    const float* p_o   = (const float*)d_in[22];
    const float* ab    = (const float*)d_in[23];
    const int*   bidx  = (const int*)d_in[24];
    float* out = (float*)d_out;
    int n_off = in_sizes[23] / HEADS;

    char* ws = (char*)d_ws;
    float* qin    = (float*)(ws + O_QIN);
    short* qinT_h = (short*)(ws + O_QINT_HI);
    short* qinT_l = (short*)(ws + O_QINT_LO);
    short* xT_h   = (short*)(ws + O_XT_HI);
    short* xT_l   = (short*)(ws + O_XT_LO);
    float* vlocal = (float*)(ws + O_VLOCAL);
    float* attnT  = (float*)(ws + O_ATTNT);
    short* gT_h   = (short*)(ws + O_GT_HI);
    short* gT_l   = (short*)(ws + O_GT_LO);
    short* q_h    = (short*)(ws + O_Q_HI);
    short* q_l    = (short*)(ws + O_Q_LO);
    short* k_h    = (short*)(ws + O_K_HI);
    short* k_l    = (short*)(ws + O_K_LO);
    short* v_h    = (short*)(ws + O_V_HI);
    short* v_l    = (short*)(ws + O_V_LO);
    float* biasM  = (float*)(ws + O_BIASM);
    short* w_h    = (short*)(ws + O_W_HI);
    short* w_l    = (short*)(ws + O_W_LO);

    // 1. qin (fp32)
    qin_kernel<<<dim3(DIMC, BATCH), 256, 0, stream>>>(x, ql_w, ql_b, qin);
    // 2. weight splits
    wsplit_kernel<<<dim3(1920), 256, 0, stream>>>(qp_w, k_w, v_w, p_w, w_h, w_l);
    // 3. qin -> qinT
    tsplit_kernel<<<dim3(QPAD / 32, DIMC / 32, BATCH), 256, 0, stream>>>(qin, qinT_h, qinT_l, DIMC, NN2, QPAD);
    // 4. q projection
    gemm_split_kernel<<<dim3(2, 1, BATCH), 256, 0, stream>>>(
        w_h + 0, w_l + 0, qinT_h, qinT_l, qp_b, qp_s, qp_o,
        nullptr, q_h, q_l, 1, DIMC, NN2, QPAD);
    // 5. x -> xT
    tsplit_kernel<<<dim3(XPAD / 32, DIMC / 32, BATCH), 256, 0, stream>>>(x, xT_h, xT_l, DIMC, NN, XPAD);
    // 6. k projection
    gemm_split_kernel<<<dim3(7, 1, BATCH), 256, 0, stream>>>(
        w_h + 49152, w_l + 49152, xT_h, xT_l, k_b, k_s, k_o,
        nullptr, k_h, k_l, 1, DIMC, NN, XPAD);
    // 7. v projection
    gemm_split_kernel<<<dim3(7, 4, BATCH), 256, 0, stream>>>(
        w_h + 98304, w_l + 98304, xT_h, xT_l, v_b, v_s, v_o,
        nullptr, v_h, v_l, 1, DIMC, NN, XPAD);
    // 8. v_local
    vlocal_kernel<<<dim3(DH, BATCH), 256, 0, stream>>>(v_h, v_l, vl_w, vl_b, vl_s, vl_o, vlocal);
    // 9. bias expand
    bias_expand_kernel<<<dim3((NN2 * NN + 255) / 256, HEADS), 256, 0, stream>>>(ab, bidx, biasM, n_off);
    // 10. attention (flat grid, in-kernel XCD remap)
    attn_mfma3_kernel<<<dim3(4 * HEADS * BATCH), 256, 0, stream>>>(q_h, q_l, k_h, k_l, v_h, v_l, biasM, attnT);
    // 11. gelu
    gelu_addT_kernel<<<dim3(QPAD / 32, DH / 32, BATCH), 256, 0, stream>>>(attnT, vlocal, gT_h, gT_l);
    // 12. output projection
    gemm_split_kernel<<<dim3(2, 3, BATCH), 256, 0, stream>>>(
        w_h + 294912, w_l + 294912, gT_h, gT_l, p_b, p_s, p_o,
        out, nullptr, nullptr, 0, DH, NN2, QPAD);
}

// Round 6
// 563.646 us; speedup vs baseline: 1.0467x; 1.0467x over previous
//
#include <hip/hip_runtime.h>
#include <math.h>

#define BATCH   64
#define DIMC    384
#define KEY_DIM 16
#define HEADS   8
#define DD      64
#define DH      512
#define NH_KD   128
#define RES     28
#define RES2    14
#define NN      784
#define NN2     196
#define OUT_DIM 384
#define SCALE   0.25f
#define XPAD    896     // 7*128
#define QPAD    256     // 2*128
#define KPAD    832     // 13*64 (key padding for KT/V/bias rows)

typedef __attribute__((ext_vector_type(8))) short bf16x8;
typedef __attribute__((ext_vector_type(4))) float f32x4;

#define MFMA32(a, b, c) __builtin_amdgcn_mfma_f32_16x16x32_bf16(a, b, c, 0, 0, 0)

__device__ inline short f2bf(float f) {
    unsigned u = __float_as_uint(f);
    unsigned r = (u + 0x7fff + ((u >> 16) & 1)) >> 16;
    return (short)r;
}
__device__ inline float bf2f(short h) {
    return __uint_as_float(((unsigned)(unsigned short)h) << 16);
}

// ---- ws byte offsets (peak 208.5 MB) ----
#define O_QIN      0u           // fp32 64*384*196          (steps 1-3)
#define O_QINT_HI  20971520u    // bf16 64*256*384          (steps 3-4)
#define O_QINT_LO  33554432u
#define O_XT_HI    0u           // bf16 64*896*384          (steps 5-7)
#define O_XT_LO    44040192u
#define O_QT       88080384u    // packed 64*8*256*32*2B    (step 4 -> 10)
#define O_KT       96468992u    // packed 64*8*832*32*2B    (step 6 -> 10)
#define O_V        123731968u   // bf16 64*512*832*2B       (step 7 -> 10)
#define O_VLOCAL   178257920u   // fp32 64*512*196          (step 8 -> 11)
#define O_BIASB    203948032u   // bf16 8*196*832           (step 9 -> 10)
#define O_W_HI     206557184u   // bf16 491520              (step 2 -> 12)
#define O_W_LO     207540224u
#define O_ATTNT    0u           // fp32 64*196*512          (step 10 -> 11; xT dead)
#define O_GT_HI    25690112u    // bf16 64*256*512          (step 11 -> 12)
#define O_GT_LO    42467328u

// ---------------- qin = dwconv3x3 s2 (pad 1) + pool ----------------
__global__ void qin_kernel(const float* __restrict__ x, const float* __restrict__ ql_w,
                           const float* __restrict__ ql_b, float* __restrict__ qin) {
    int c = blockIdx.x, b = blockIdx.y, n2 = threadIdx.x;
    if (n2 >= NN2) return;
    int i = n2 / RES2, j = n2 % RES2;
    const float* xp = x + ((size_t)b * DIMC + c) * (RES * RES);
    const float* w  = ql_w + c * 9;
    float acc = ql_b[c];
    #pragma unroll
    for (int di = 0; di < 3; ++di) {
        int r = 2 * i + di - 1;
        if (r < 0 || r >= RES) continue;
        #pragma unroll
        for (int dj = 0; dj < 3; ++dj) {
            int cc = 2 * j + dj - 1;
            if (cc < 0 || cc >= RES) continue;
            acc += xp[r * RES + cc] * w[di * 3 + dj];
        }
    }
    acc += xp[(2 * i) * RES + 2 * j];
    qin[((size_t)b * DIMC + c) * NN2 + n2] = acc;
}

// ---------------- weight split ----------------
__global__ void wsplit_kernel(const float* __restrict__ w0, const float* __restrict__ w1,
                              const float* __restrict__ w2, const float* __restrict__ w3,
                              short* __restrict__ hi, short* __restrict__ lo) {
    int i = blockIdx.x * 256 + threadIdx.x;
    if (i >= 491520) return;
    const float* src; int j = i;
    if (j < 49152) src = w0;
    else if (j < 98304) { src = w1; j -= 49152; }
    else if (j < 294912) { src = w2; j -= 98304; }
    else { src = w3; j -= 294912; }
    float v = src[j];
    short h = f2bf(v);
    hi[i] = h;
    lo[i] = f2bf(v - bf2f(h));
}

// ---------------- transpose + split: [b][C][N] f32 -> [b][Npad][C] bf16 hi/lo ----------------
__global__ void tsplit_kernel(const float* __restrict__ in, short* __restrict__ out_hi,
                              short* __restrict__ out_lo, int C, int N, int Npad) {
    __shared__ float tile[32][33];
    int ntb = blockIdx.x * 32, ctb = blockIdx.y * 32, b = blockIdx.z;
    int tn = threadIdx.x & 31, tc4 = threadIdx.x >> 5;
    #pragma unroll
    for (int i = 0; i < 4; ++i) {
        int c = tc4 + i * 8;
        int n = ntb + tn;
        tile[c][tn] = (n < N) ? in[((size_t)b * C + ctb + c) * N + n] : 0.f;
    }
    __syncthreads();
    int tc = threadIdx.x & 31, tn4 = threadIdx.x >> 5;
    #pragma unroll
    for (int i = 0; i < 4; ++i) {
        int n = tn4 + i * 8;
        float v = tile[tc][n];
        short h = f2bf(v);
        size_t o = ((size_t)b * Npad + ntb + n) * C + ctb + tc;
        out_hi[o] = h;
        out_lo[o] = f2bf(v - bf2f(h));
    }
}

// ---------------- split-bf16 MFMA GEMM ----------------
// mode 0: fp32 out [b][O][Nn]
// mode 1: bf16 out [b][O][NPADo], zero-padded cols Nn..NPADo-1
// mode 2: packed [b*8+h][NPADo][16hi|16lo] (O must be 128), zero-padded cols
__global__ __launch_bounds__(256)
void gemm_split_kernel(const short* __restrict__ Ag_hi, const short* __restrict__ Ag_lo,
                       const short* __restrict__ Bg_hi, const short* __restrict__ Bg_lo,
                       const float* __restrict__ bias, const float* __restrict__ s,
                       const float* __restrict__ off,
                       float* __restrict__ out_f, short* __restrict__ out_b,
                       int mode, int C, int Nn, int Npad, int NPADo) {
    __shared__ __align__(16) short Ah[128 * 32], Al[128 * 32], Bh[128 * 32], Bl[128 * 32];

    const int t = threadIdx.x;
    const int n0 = blockIdx.x * 128, o0 = blockIdx.y * 128, b = blockIdx.z;
    const int O = gridDim.y * 128;
    const int lane = t & 63, wid = t >> 6;
    const int wm = wid & 1, wn = wid >> 1;
    const int lr = lane & 15, kg = lane >> 4;

    f32x4 acc[4][4];
    #pragma unroll
    for (int m = 0; m < 4; ++m)
        #pragma unroll
        for (int n = 0; n < 4; ++n)
            acc[m][n] = (f32x4){0.f, 0.f, 0.f, 0.f};

    const int srow = t >> 2;
    const int sch  = (t & 3) * 8;
    const size_t aBase = (size_t)(o0 + srow) * C + sch;
    const size_t bBase = ((size_t)b * Npad + n0 + srow) * C + sch;
    const size_t rstep = (size_t)64 * C;

    bf16x8 rA[2], rAl[2], rB[2], rBl[2];
    #pragma unroll
    for (int p = 0; p < 2; ++p) {
        rA[p]  = *(const bf16x8*)(Ag_hi + aBase + p * rstep);
        rAl[p] = *(const bf16x8*)(Ag_lo + aBase + p * rstep);
        rB[p]  = *(const bf16x8*)(Bg_hi + bBase + p * rstep);
        rBl[p] = *(const bf16x8*)(Bg_lo + bBase + p * rstep);
    }

    for (int k0 = 0;; k0 += 32) {
        #pragma unroll
        for (int p = 0; p < 2; ++p) {
            int la = (srow + p * 64) * 32 + sch;
            *(bf16x8*)&Ah[la] = rA[p];
            *(bf16x8*)&Al[la] = rAl[p];
            *(bf16x8*)&Bh[la] = rB[p];
            *(bf16x8*)&Bl[la] = rBl[p];
        }
        __syncthreads();

        if (k0 + 32 < C) {
            #pragma unroll
            for (int p = 0; p < 2; ++p) {
                rA[p]  = *(const bf16x8*)(Ag_hi + aBase + (k0 + 32) + p * rstep);
                rAl[p] = *(const bf16x8*)(Ag_lo + aBase + (k0 + 32) + p * rstep);
                rB[p]  = *(const bf16x8*)(Bg_hi + bBase + (k0 + 32) + p * rstep);
                rBl[p] = *(const bf16x8*)(Bg_lo + bBase + (k0 + 32) + p * rstep);
            }
        }

        bf16x8 ah[4], al[4];
        #pragma unroll
        for (int m = 0; m < 4; ++m) {
            int row = wm * 64 + m * 16 + lr;
            ah[m] = *(const bf16x8*)&Ah[row * 32 + kg * 8];
            al[m] = *(const bf16x8*)&Al[row * 32 + kg * 8];
        }
        #pragma unroll
        for (int nf = 0; nf < 4; ++nf) {
            int row = wn * 64 + nf * 16 + lr;
            bf16x8 bh = *(const bf16x8*)&Bh[row * 32 + kg * 8];
            bf16x8 bl = *(const bf16x8*)&Bl[row * 32 + kg * 8];
            #pragma unroll
            for (int m = 0; m < 4; ++m) {
                acc[m][nf] = MFMA32(ah[m], bh, acc[m][nf]);
                acc[m][nf] = MFMA32(ah[m], bl, acc[m][nf]);
                acc[m][nf] = MFMA32(al[m], bh, acc[m][nf]);
            }
        }
        if (k0 + 32 >= C) break;
        __syncthreads();
    }

    #pragma unroll
    for (int m = 0; m < 4; ++m) {
        #pragma unroll
        for (int nf = 0; nf < 4; ++nf) {
            int col = n0 + wn * 64 + nf * 16 + lr;
            if (mode == 0) {
                if (col >= Nn) continue;
                #pragma unroll
                for (int r = 0; r < 4; ++r) {
                    int row = o0 + wm * 64 + m * 16 + kg * 4 + r;
                    float a = s[row];
                    float v = acc[m][nf][r] * a + (bias[row] * a + off[row]);
                    out_f[((size_t)b * O + row) * Nn + col] = v;
                }
            } else if (mode == 1) {
                if (col >= NPADo) continue;
                #pragma unroll
                for (int r = 0; r < 4; ++r) {
                    int row = o0 + wm * 64 + m * 16 + kg * 4 + r;
                    short hv = 0;
                    if (col < Nn) {
                        float a = s[row];
                        hv = f2bf(acc[m][nf][r] * a + (bias[row] * a + off[row]));
                    }
                    out_b[((size_t)b * O + row) * NPADo + col] = hv;
                }
            } else {
                if (col >= NPADo) continue;
                int hh = (o0 + wm * 64 + m * 16) >> 4;   // head index (O=128)
                short4 h4, l4;
                #pragma unroll
                for (int r = 0; r < 4; ++r) {
                    int row = o0 + wm * 64 + m * 16 + kg * 4 + r;
                    float v = 0.f;
                    if (col < Nn) {
                        float a = s[row];
                        v = acc[m][nf][r] * a + (bias[row] * a + off[row]);
                    }
                    short hv = f2bf(v);
                    ((short*)&h4)[r] = hv;
                    ((short*)&l4)[r] = f2bf(v - bf2f(hv));
                }
                size_t base = ((size_t)(b * 8 + hh) * NPADo + col) * 32 + kg * 4;
                *(short4*)(out_b + base)      = h4;
                *(short4*)(out_b + base + 16) = l4;
            }
        }
    }
}

// ---------------- v_local = bn(dwconv3x3 s2 over v) ; v bf16 [b][512][832] ----------------
__global__ void vlocal_kernel(const short* __restrict__ v,
                              const float* __restrict__ vl_w, const float* __restrict__ vl_b,
                              const float* __restrict__ vl_s, const float* __restrict__ vl_o,
                              float* __restrict__ vlocal) {
    int c = blockIdx.x, b = blockIdx.y, n2 = threadIdx.x;
    if (n2 >= NN2) return;
    int i = n2 / RES2, j = n2 % RES2;
    const size_t base = ((size_t)b * DH + c) * KPAD;
    const float* w = vl_w + c * 9;
    float acc = vl_b[c];
    #pragma unroll
    for (int di = 0; di < 3; ++di) {
        int r = 2 * i + di - 1;
        if (r < 0 || r >= RES) continue;
        #pragma unroll
        for (int dj = 0; dj < 3; ++dj) {
            int cc = 2 * j + dj - 1;
            if (cc < 0 || cc >= RES) continue;
            acc += bf2f(v[base + r * RES + cc]) * w[di * 3 + dj];
        }
    }
    vlocal[((size_t)b * DH + c) * NN2 + n2] = acc * vl_s[c] + vl_o[c];
}

// ---------------- bias expand -> bf16, padded rows of 832 ----------------
__global__ void biasB_expand_kernel(const float* __restrict__ ab, const int* __restrict__ bidx,
                                    short* __restrict__ biasB, int n_off) {
    int i = blockIdx.x * 256 + threadIdx.x;
    int h = blockIdx.y;
    if (i >= NN2 * KPAD) return;
    int q = i / KPAD, key = i - q * KPAD;
    short v = 0;
    if (key < NN) v = f2bf(ab[h * n_off + bidx[q * NN + key]]);
    biasB[(size_t)h * NN2 * KPAD + i] = v;
}

// ---------------- MFMA attention v4: zero barriers, direct-global operands ----------------
__global__ __launch_bounds__(256)
void attn_mfma4_kernel(const short* __restrict__ QT, const short* __restrict__ KT,
                       const short* __restrict__ V, const short* __restrict__ biasB,
                       float* __restrict__ outT) {
    __shared__ __align__(16) char Ps[4][2048];   // wave-private: 16 q rows x 128B keys

    const int t = threadIdx.x;
    const int bid = blockIdx.x;           // XCD remap: head <-> XCD, qt innermost
    const int h  = bid & 7;
    const int qt = (bid >> 3) & 3;
    const int b  = bid >> 5;

    const int lane = t & 63, wid = t >> 6;
    const int lr = lane & 15, kg = lane >> 4;
    const int qg = qt * 64 + wid * 16 + lr;
    const int qsafe = (qg < NN2) ? qg : (NN2 - 1);

    // Q fragments in registers (one-time loads)
    const short* qrow = QT + ((size_t)(b * 8 + h) * QPAD + qg) * 32;
    bf16x8 qb1 = *(const bf16x8*)(qrow + (kg & 1) * 8);           // [Qhi|Qhi]
    bf16x8 qb2 = (bf16x8){0, 0, 0, 0, 0, 0, 0, 0};                // [Qlo|0]
    if (kg < 2) qb2 = *(const bf16x8*)(qrow + 16 + kg * 8);

    const short* kbase = KT + (size_t)(b * 8 + h) * KPAD * 32;
    const short* vbase = V + ((size_t)b * DH + h * DD) * KPAD;
    const short* bbase = biasB + ((size_t)h * NN2 + qsafe) * KPAD;

    f32x4 acc[4];
    #pragma unroll
    for (int n = 0; n < 4; ++n) acc[n] = (f32x4){0.f, 0.f, 0.f, 0.f};
    float sacc = 0.f;
    char* Psw = &Ps[wid][0];
    const int swz = (lr & 7) << 4;

    for (int tile = 0; tile < 13; ++tile) {
        const int k0 = tile * 64;
        // QK^T: A = KT rows (keys, [hi|lo] packed), B = Q
        #pragma unroll
        for (int nt = 0; nt < 4; ++nt) {
            bf16x8 ka = *(const bf16x8*)(kbase + (size_t)(k0 + nt * 16 + lr) * 32 + kg * 8);
            f32x4 sc = (f32x4){0.f, 0.f, 0.f, 0.f};
            sc = MFMA32(ka, qb1, sc);      // Khi*Qhi + Klo*Qhi
            sc = MFMA32(ka, qb2, sc);      // Khi*Qlo
            int keyb = k0 + nt * 16 + kg * 4;
            bool kvalid = keyb < NN;       // 784 % 4 == 0: group-uniform
            short4 b4 = *(const short4*)(bbase + keyb);
            short4 pk;
            #pragma unroll
            for (int r = 0; r < 4; ++r) {
                float sv = sc[r] * SCALE + bf2f(((const short*)&b4)[r]);
                float pv = kvalid ? __expf(sv) : 0.f;
                sacc += pv;
                ((short*)&pk)[r] = f2bf(pv);
            }
            *(short4*)(Psw + lr * 128 + ((nt * 32 + kg * 8) ^ swz)) = pk;
        }
        // PV: A = P (LDS), B = V direct-global (bf16, zero-padded keys)
        #pragma unroll
        for (int ks = 0; ks < 2; ++ks) {
            bf16x8 pa = *(const bf16x8*)(Psw + lr * 128 + ((ks * 64 + kg * 16) ^ swz));
            #pragma unroll
            for (int nt = 0; nt < 4; ++nt) {
                bf16x8 vf = *(const bf16x8*)(vbase + (size_t)(nt * 16 + lr) * KPAD + k0 + ks * 32 + kg * 8);
                acc[nt] = MFMA32(pa, vf, acc[nt]);
            }
        }
    }

    sacc += __shfl_xor(sacc, 16, 64);
    sacc += __shfl_xor(sacc, 32, 64);

    #pragma unroll
    for (int r = 0; r < 4; ++r) {
        int qrow_ = qt * 64 + wid * 16 + kg * 4 + r;
        if (qrow_ >= NN2) continue;
        float inv = 1.f / __shfl(sacc, kg * 4 + r, 64);
        #pragma unroll
        for (int nt = 0; nt < 4; ++nt) {
            int d = nt * 16 + lr;
            outT[((size_t)b * NN2 + qrow_) * DH + h * DD + d] = acc[nt][r] * inv;
        }
    }
}

// ---------------- gelu(attnT + vlocal^T) -> gT hi/lo [b][256][512] ----------------
__global__ void gelu_addT_kernel(const float* __restrict__ aT, const float* __restrict__ vloc,
                                 short* __restrict__ g_hi, short* __restrict__ g_lo) {
    __shared__ float tile[32][33];
    int ntb = blockIdx.x * 32, ctb = blockIdx.y * 32, b = blockIdx.z;
    int tn = threadIdx.x & 31, tc4 = threadIdx.x >> 5;
    #pragma unroll
    for (int i = 0; i < 4; ++i) {
        int c = tc4 + i * 8;
        int n = ntb + tn;
        tile[c][tn] = (n < NN2) ? vloc[((size_t)b * DH + ctb + c) * NN2 + n] : 0.f;
    }
    __syncthreads();
    int tc = threadIdx.x & 31, tn4 = threadIdx.x >> 5;
    #pragma unroll
    for (int i = 0; i < 4; ++i) {
        int n = ntb + tn4 + i * 8;
        float g = 0.f;
        if (n < NN2) {
            float sum = aT[((size_t)b * NN2 + n) * DH + ctb + tc] + tile[tc][tn4 + i * 8];
            g = 0.5f * sum * (1.f + erff(sum * 0.70710678118654752440f));
        }
        short hh = f2bf(g);
        size_t o = ((size_t)b * QPAD + n) * DH + ctb + tc;
        g_hi[o] = hh;
        g_lo[o] = f2bf(g - bf2f(hh));
    }
}

extern "C" void kernel_launch(void* const* d_in, const int* in_sizes, int n_in,
                              void* d_out, int out_size, void* d_ws, size_t ws_size,
                              hipStream_t stream) {
    const float* x     = (const float*)d_in[0];
    const float* ql_w  = (const float*)d_in[1];
    const float* ql_b  = (const float*)d_in[2];
    const float* qp_w  = (const float*)d_in[3];
    const float* qp_b  = (const float*)d_in[4];
    const float* qp_s  = (const float*)d_in[5];
    const float* qp_o  = (const float*)d_in[6];
    const float* k_w   = (const float*)d_in[7];
    const float* k_b   = (const float*)d_in[8];
    const float* k_s   = (const float*)d_in[9];
    const float* k_o   = (const float*)d_in[10];
    const float* v_w   = (const float*)d_in[11];
    const float* v_b   = (const float*)d_in[12];
    const float* v_s   = (const float*)d_in[13];
    const float* v_o   = (const float*)d_in[14];
    const float* vl_w  = (const float*)d_in[15];
    const float* vl_b  = (const float*)d_in[16];
    const float* vl_s  = (const float*)d_in[17];
    const float* vl_o  = (const float*)d_in[18];
    const float* p_w   = (const float*)d_in[19];
    const float* p_b   = (const float*)d_in[20];
    const float* p_s   = (const float*)d_in[21];
    const float* p_o   = (const float*)d_in[22];
    const float* ab    = (const float*)d_in[23];
    const int*   bidx  = (const int*)d_in[24];
    float* out = (float*)d_out;
    int n_off = in_sizes[23] / HEADS;

    char* ws = (char*)d_ws;
    float* qin    = (float*)(ws + O_QIN);
    short* qinT_h = (short*)(ws + O_QINT_HI);
    short* qinT_l = (short*)(ws + O_QINT_LO);
    short* xT_h   = (short*)(ws + O_XT_HI);
    short* xT_l   = (short*)(ws + O_XT_LO);
    short* QT     = (short*)(ws + O_QT);
    short* KT     = (short*)(ws + O_KT);
    short* Vb     = (short*)(ws + O_V);
    float* vlocal = (float*)(ws + O_VLOCAL);
    short* biasB  = (short*)(ws + O_BIASB);
    short* w_h    = (short*)(ws + O_W_HI);
    short* w_l    = (short*)(ws + O_W_LO);
    float* attnT  = (float*)(ws + O_ATTNT);
    short* gT_h   = (short*)(ws + O_GT_HI);
    short* gT_l   = (short*)(ws + O_GT_LO);

    // 1. qin (fp32)
    qin_kernel<<<dim3(DIMC, BATCH), 256, 0, stream>>>(x, ql_w, ql_b, qin);
    // 2. weight splits
    wsplit_kernel<<<dim3(1920), 256, 0, stream>>>(qp_w, k_w, v_w, p_w, w_h, w_l);
    // 3. qin -> qinT
    tsplit_kernel<<<dim3(QPAD / 32, DIMC / 32, BATCH), 256, 0, stream>>>(qin, qinT_h, qinT_l, DIMC, NN2, QPAD);
    // 4. q projection -> QT packed [b,h][256][32]
    gemm_split_kernel<<<dim3(2, 1, BATCH), 256, 0, stream>>>(
        w_h + 0, w_l + 0, qinT_h, qinT_l, qp_b, qp_s, qp_o,
        nullptr, QT, 2, DIMC, NN2, QPAD, QPAD);
    // 5. x -> xT
    tsplit_kernel<<<dim3(XPAD / 32, DIMC / 32, BATCH), 256, 0, stream>>>(x, xT_h, xT_l, DIMC, NN, XPAD);
    // 6. k projection -> KT packed [b,h][832][32]
    gemm_split_kernel<<<dim3(7, 1, BATCH), 256, 0, stream>>>(
        w_h + 49152, w_l + 49152, xT_h, xT_l, k_b, k_s, k_o,
        nullptr, KT, 2, DIMC, NN, XPAD, KPAD);
    // 7. v projection -> bf16 [b][512][832]
    gemm_split_kernel<<<dim3(7, 4, BATCH), 256, 0, stream>>>(
        w_h + 98304, w_l + 98304, xT_h, xT_l, v_b, v_s, v_o,
        nullptr, Vb, 1, DIMC, NN, XPAD, KPAD);
    // 8. v_local
    vlocal_kernel<<<dim3(DH, BATCH), 256, 0, stream>>>(Vb, vl_w, vl_b, vl_s, vl_o, vlocal);
    // 9. bias expand (bf16, padded)
    biasB_expand_kernel<<<dim3((NN2 * KPAD + 255) / 256, HEADS), 256, 0, stream>>>(ab, bidx, biasB, n_off);
    // 10. attention (no barriers, direct-global operands)
    attn_mfma4_kernel<<<dim3(4 * HEADS * BATCH), 256, 0, stream>>>(QT, KT, Vb, biasB, attnT);
    // 11. gelu
    gelu_addT_kernel<<<dim3(QPAD / 32, DH / 32, BATCH), 256, 0, stream>>>(attnT, vlocal, gT_h, gT_l);
    // 12. output projection
    gemm_split_kernel<<<dim3(2, 3, BATCH), 256, 0, stream>>>(
        w_h + 294912, w_l + 294912, gT_h, gT_l, p_b, p_s, p_o,
        out, nullptr, 0, DH, NN2, QPAD, 0);
}

// Round 7
// 501.447 us; speedup vs baseline: 1.1766x; 1.1240x over previous
//
#include <hip/hip_runtime.h>
#include <math.h>

#define BATCH   64
#define DIMC    384
#define KEY_DIM 16
#define HEADS   8
#define DD      64
#define DH      512
#define NH_KD   128
#define RES     28
#define RES2    14
#define NN      784
#define NN2     196
#define OUT_DIM 384
#define SCALE   0.25f
#define XPAD    896     // 7*128
#define QPAD    256     // 2*128
#define KPAD    832     // 13*64

typedef __attribute__((ext_vector_type(8))) short bf16x8;
typedef __attribute__((ext_vector_type(4))) float f32x4;

#define MFMA32(a, b, c) __builtin_amdgcn_mfma_f32_16x16x32_bf16(a, b, c, 0, 0, 0)

__device__ inline short f2bf(float f) {
    unsigned u = __float_as_uint(f);
    unsigned r = (u + 0x7fff + ((u >> 16) & 1)) >> 16;
    return (short)r;
}
__device__ inline float bf2f(short h) {
    return __uint_as_float(((unsigned)(unsigned short)h) << 16);
}

// ---- ws byte offsets ----
#define O_QIN      0u           // fp32 qin (steps 1-3)
#define O_QINT_HI  20971520u    // bf16 qinT (steps 3-4)
#define O_XT_HI    0u           // bf16 xT (steps 5-7, overwrites qin after step 4... order-safe)
#define O_QT       88080384u    // packed QT (step 4 -> 10)
#define O_KT       96468992u    // packed KT (step 6 -> 10)
#define O_V        123731968u   // bf16 V [b][512][832] (step 7 -> 10)
#define O_VLOCAL   178257920u   // fp32 (step 8 -> 11)
#define O_BIASB    203948032u   // bf16 (step 9 -> 10)
#define O_W_HI     206557184u
#define O_W_LO     207540224u
#define O_ATTNT    0u           // fp32 (step 10 -> 11; xT dead)
#define O_GT_HI    25690112u    // (step 11 -> 12)
#define O_GT_LO    42467328u

// ---------------- qin = dwconv3x3 s2 (pad 1) + pool ----------------
__global__ void qin_kernel(const float* __restrict__ x, const float* __restrict__ ql_w,
                           const float* __restrict__ ql_b, float* __restrict__ qin) {
    int c = blockIdx.x, b = blockIdx.y, n2 = threadIdx.x;
    if (n2 >= NN2) return;
    int i = n2 / RES2, j = n2 % RES2;
    const float* xp = x + ((size_t)b * DIMC + c) * (RES * RES);
    const float* w  = ql_w + c * 9;
    float acc = ql_b[c];
    #pragma unroll
    for (int di = 0; di < 3; ++di) {
        int r = 2 * i + di - 1;
        if (r < 0 || r >= RES) continue;
        #pragma unroll
        for (int dj = 0; dj < 3; ++dj) {
            int cc = 2 * j + dj - 1;
            if (cc < 0 || cc >= RES) continue;
            acc += xp[r * RES + cc] * w[di * 3 + dj];
        }
    }
    acc += xp[(2 * i) * RES + 2 * j];
    qin[((size_t)b * DIMC + c) * NN2 + n2] = acc;
}

// ---------------- weight split ----------------
__global__ void wsplit_kernel(const float* __restrict__ w0, const float* __restrict__ w1,
                              const float* __restrict__ w2, const float* __restrict__ w3,
                              short* __restrict__ hi, short* __restrict__ lo) {
    int i = blockIdx.x * 256 + threadIdx.x;
    if (i >= 491520) return;
    const float* src; int j = i;
    if (j < 49152) src = w0;
    else if (j < 98304) { src = w1; j -= 49152; }
    else if (j < 294912) { src = w2; j -= 98304; }
    else { src = w3; j -= 294912; }
    float v = src[j];
    short h = f2bf(v);
    hi[i] = h;
    lo[i] = f2bf(v - bf2f(h));
}

// ---------------- transpose + bf16: [b][C][N] f32 -> [b][Npad][C] bf16 (hi only) ----------------
__global__ void tsplit_kernel(const float* __restrict__ in, short* __restrict__ out_hi,
                              int C, int N, int Npad) {
    __shared__ float tile[32][33];
    int ntb = blockIdx.x * 32, ctb = blockIdx.y * 32, b = blockIdx.z;
    int tn = threadIdx.x & 31, tc4 = threadIdx.x >> 5;
    #pragma unroll
    for (int i = 0; i < 4; ++i) {
        int c = tc4 + i * 8;
        int n = ntb + tn;
        tile[c][tn] = (n < N) ? in[((size_t)b * C + ctb + c) * N + n] : 0.f;
    }
    __syncthreads();
    int tc = threadIdx.x & 31, tn4 = threadIdx.x >> 5;
    #pragma unroll
    for (int i = 0; i < 4; ++i) {
        int n = tn4 + i * 8;
        out_hi[((size_t)b * Npad + ntb + n) * C + ctb + tc] = f2bf(tile[tc][n]);
    }
}

// ---------------- split-bf16 MFMA GEMM ----------------
// A = weights hi/lo; B = activations hi (+lo if BLO)
// mode 0: fp32 out [b][O][Nn]; mode 1: bf16 [b][O][NPADo] zero-padded;
// mode 2: packed [b*8+h][NPADo][16hi|16lo] (O must be 128)
template<bool BLO>
__global__ __launch_bounds__(256)
void gemm_split_kernel(const short* __restrict__ Ag_hi, const short* __restrict__ Ag_lo,
                       const short* __restrict__ Bg_hi, const short* __restrict__ Bg_lo,
                       const float* __restrict__ bias, const float* __restrict__ s,
                       const float* __restrict__ off,
                       float* __restrict__ out_f, short* __restrict__ out_b,
                       int mode, int C, int Nn, int Npad, int NPADo) {
    __shared__ __align__(16) short Ah[128 * 32], Al[128 * 32], Bh[128 * 32];
    __shared__ __align__(16) short Bl[BLO ? 128 * 32 : 64];

    const int t = threadIdx.x;
    const int n0 = blockIdx.x * 128, o0 = blockIdx.y * 128, b = blockIdx.z;
    const int O = gridDim.y * 128;
    const int lane = t & 63, wid = t >> 6;
    const int wm = wid & 1, wn = wid >> 1;
    const int lr = lane & 15, kg = lane >> 4;

    f32x4 acc[4][4];
    #pragma unroll
    for (int m = 0; m < 4; ++m)
        #pragma unroll
        for (int n = 0; n < 4; ++n)
            acc[m][n] = (f32x4){0.f, 0.f, 0.f, 0.f};

    const int srow = t >> 2;
    const int sch  = (t & 3) * 8;
    const size_t aBase = (size_t)(o0 + srow) * C + sch;
    const size_t bBase = ((size_t)b * Npad + n0 + srow) * C + sch;
    const size_t rstep = (size_t)64 * C;

    bf16x8 rA[2], rAl[2], rB[2], rBl[2];
    #pragma unroll
    for (int p = 0; p < 2; ++p) {
        rA[p]  = *(const bf16x8*)(Ag_hi + aBase + p * rstep);
        rAl[p] = *(const bf16x8*)(Ag_lo + aBase + p * rstep);
        rB[p]  = *(const bf16x8*)(Bg_hi + bBase + p * rstep);
        if constexpr (BLO) rBl[p] = *(const bf16x8*)(Bg_lo + bBase + p * rstep);
    }

    for (int k0 = 0;; k0 += 32) {
        #pragma unroll
        for (int p = 0; p < 2; ++p) {
            int la = (srow + p * 64) * 32 + sch;
            *(bf16x8*)&Ah[la] = rA[p];
            *(bf16x8*)&Al[la] = rAl[p];
            *(bf16x8*)&Bh[la] = rB[p];
            if constexpr (BLO) *(bf16x8*)&Bl[la] = rBl[p];
        }
        __syncthreads();

        if (k0 + 32 < C) {
            #pragma unroll
            for (int p = 0; p < 2; ++p) {
                rA[p]  = *(const bf16x8*)(Ag_hi + aBase + (k0 + 32) + p * rstep);
                rAl[p] = *(const bf16x8*)(Ag_lo + aBase + (k0 + 32) + p * rstep);
                rB[p]  = *(const bf16x8*)(Bg_hi + bBase + (k0 + 32) + p * rstep);
                if constexpr (BLO) rBl[p] = *(const bf16x8*)(Bg_lo + bBase + (k0 + 32) + p * rstep);
            }
        }

        bf16x8 ah[4], al[4];
        #pragma unroll
        for (int m = 0; m < 4; ++m) {
            int row = wm * 64 + m * 16 + lr;
            ah[m] = *(const bf16x8*)&Ah[row * 32 + kg * 8];
            al[m] = *(const bf16x8*)&Al[row * 32 + kg * 8];
        }
        #pragma unroll
        for (int nf = 0; nf < 4; ++nf) {
            int row = wn * 64 + nf * 16 + lr;
            bf16x8 bh = *(const bf16x8*)&Bh[row * 32 + kg * 8];
            #pragma unroll
            for (int m = 0; m < 4; ++m) {
                acc[m][nf] = MFMA32(ah[m], bh, acc[m][nf]);
                acc[m][nf] = MFMA32(al[m], bh, acc[m][nf]);
            }
            if constexpr (BLO) {
                bf16x8 bl = *(const bf16x8*)&Bl[row * 32 + kg * 8];
                #pragma unroll
                for (int m = 0; m < 4; ++m)
                    acc[m][nf] = MFMA32(ah[m], bl, acc[m][nf]);
            }
        }
        if (k0 + 32 >= C) break;
        __syncthreads();
    }

    #pragma unroll
    for (int m = 0; m < 4; ++m) {
        #pragma unroll
        for (int nf = 0; nf < 4; ++nf) {
            int col = n0 + wn * 64 + nf * 16 + lr;
            if (mode == 0) {
                if (col >= Nn) continue;
                #pragma unroll
                for (int r = 0; r < 4; ++r) {
                    int row = o0 + wm * 64 + m * 16 + kg * 4 + r;
                    float a = s[row];
                    out_f[((size_t)b * O + row) * Nn + col] =
                        acc[m][nf][r] * a + (bias[row] * a + off[row]);
                }
            } else if (mode == 1) {
                if (col >= NPADo) continue;
                #pragma unroll
                for (int r = 0; r < 4; ++r) {
                    int row = o0 + wm * 64 + m * 16 + kg * 4 + r;
                    short hv = 0;
                    if (col < Nn) {
                        float a = s[row];
                        hv = f2bf(acc[m][nf][r] * a + (bias[row] * a + off[row]));
                    }
                    out_b[((size_t)b * O + row) * NPADo + col] = hv;
                }
            } else {
                if (col >= NPADo) continue;
                int hh = (o0 + wm * 64 + m * 16) >> 4;
                short4 h4, l4;
                #pragma unroll
                for (int r = 0; r < 4; ++r) {
                    int row = o0 + wm * 64 + m * 16 + kg * 4 + r;
                    float v = 0.f;
                    if (col < Nn) {
                        float a = s[row];
                        v = acc[m][nf][r] * a + (bias[row] * a + off[row]);
                    }
                    short hv = f2bf(v);
                    ((short*)&h4)[r] = hv;
                    ((short*)&l4)[r] = f2bf(v - bf2f(hv));
                }
                size_t base = ((size_t)(b * 8 + hh) * NPADo + col) * 32 + kg * 4;
                *(short4*)(out_b + base)      = h4;
                *(short4*)(out_b + base + 16) = l4;
            }
        }
    }
}

// ---------------- v_local ----------------
__global__ void vlocal_kernel(const short* __restrict__ v,
                              const float* __restrict__ vl_w, const float* __restrict__ vl_b,
                              const float* __restrict__ vl_s, const float* __restrict__ vl_o,
                              float* __restrict__ vlocal) {
    int c = blockIdx.x, b = blockIdx.y, n2 = threadIdx.x;
    if (n2 >= NN2) return;
    int i = n2 / RES2, j = n2 % RES2;
    const size_t base = ((size_t)b * DH + c) * KPAD;
    const float* w = vl_w + c * 9;
    float acc = vl_b[c];
    #pragma unroll
    for (int di = 0; di < 3; ++di) {
        int r = 2 * i + di - 1;
        if (r < 0 || r >= RES) continue;
        #pragma unroll
        for (int dj = 0; dj < 3; ++dj) {
            int cc = 2 * j + dj - 1;
            if (cc < 0 || cc >= RES) continue;
            acc += bf2f(v[base + r * RES + cc]) * w[di * 3 + dj];
        }
    }
    vlocal[((size_t)b * DH + c) * NN2 + n2] = acc * vl_s[c] + vl_o[c];
}

// ---------------- bias expand -> bf16, padded rows of 832 ----------------
__global__ void biasB_expand_kernel(const float* __restrict__ ab, const int* __restrict__ bidx,
                                    short* __restrict__ biasB, int n_off) {
    int i = blockIdx.x * 256 + threadIdx.x;
    int h = blockIdx.y;
    if (i >= NN2 * KPAD) return;
    int q = i / KPAD, key = i - q * KPAD;
    short v = 0;
    if (key < NN) v = f2bf(ab[h * n_off + bidx[q * NN + key]]);
    biasB[(size_t)h * NN2 * KPAD + i] = v;
}

// ---------------- MFMA attention v5: zero barriers + register pipeline ----------------
__global__ __launch_bounds__(256)
void attn_mfma5_kernel(const short* __restrict__ QT, const short* __restrict__ KT,
                       const short* __restrict__ V, const short* __restrict__ biasB,
                       float* __restrict__ outT) {
    __shared__ __align__(16) char Ps[4][2048];

    const int t = threadIdx.x;
    const int bid = blockIdx.x;           // head <-> XCD, qt innermost
    const int h  = bid & 7;
    const int qt = (bid >> 3) & 3;
    const int b  = bid >> 5;

    const int lane = t & 63, wid = t >> 6;
    const int lr = lane & 15, kg = lane >> 4;
    const int qg = qt * 64 + wid * 16 + lr;
    const int qsafe = (qg < NN2) ? qg : (NN2 - 1);

    const short* qrow = QT + ((size_t)(b * 8 + h) * QPAD + qg) * 32;
    bf16x8 qb1 = *(const bf16x8*)(qrow + (kg & 1) * 8);           // [Qhi|Qhi]
    bf16x8 qb2 = (bf16x8){0, 0, 0, 0, 0, 0, 0, 0};                // [Qlo|0]
    if (kg < 2) qb2 = *(const bf16x8*)(qrow + 16 + kg * 8);

    const short* kbase = KT + (size_t)(b * 8 + h) * KPAD * 32;
    const short* vbase = V + ((size_t)b * DH + h * DD) * KPAD;
    const short* bbase = biasB + ((size_t)h * NN2 + qsafe) * KPAD;

    f32x4 acc[4];
    #pragma unroll
    for (int n = 0; n < 4; ++n) acc[n] = (f32x4){0.f, 0.f, 0.f, 0.f};
    float sacc = 0.f;
    char* Psw = &Ps[wid][0];
    const int swz = (lr & 7) << 4;

    bf16x8 kaA[4], kaB[4];
    short4 b4A[4], b4B[4];

    auto LOADKB = [&](int tile, bf16x8* ka, short4* b4) {
        int k0 = tile * 64;
        #pragma unroll
        for (int nt = 0; nt < 4; ++nt) {
            ka[nt] = *(const bf16x8*)(kbase + (size_t)(k0 + nt * 16 + lr) * 32 + kg * 8);
            b4[nt] = *(const short4*)(bbase + k0 + nt * 16 + kg * 4);
        }
    };

    auto COMPUTE = [&](int tile, const bf16x8* ka, const short4* b4,
                       int pft, bf16x8* kaN, short4* b4N) {
        const int k0 = tile * 64;
        // issue all V loads for this tile first (latency hidden by QK+softmax)
        bf16x8 vf[8];
        #pragma unroll
        for (int ks = 0; ks < 2; ++ks)
            #pragma unroll
            for (int nt = 0; nt < 4; ++nt)
                vf[ks * 4 + nt] = *(const bf16x8*)(vbase + (size_t)(nt * 16 + lr) * KPAD
                                                   + k0 + ks * 32 + kg * 8);
        // prefetch next tile's K + bias
        if (pft >= 0) LOADKB(pft, kaN, b4N);

        // QK^T: A = K rows ([hi|lo] packed), B = Q
        #pragma unroll
        for (int nt = 0; nt < 4; ++nt) {
            f32x4 sc = (f32x4){0.f, 0.f, 0.f, 0.f};
            sc = MFMA32(ka[nt], qb1, sc);
            sc = MFMA32(ka[nt], qb2, sc);
            int keyb = k0 + nt * 16 + kg * 4;
            bool kvalid = keyb < NN;
            short4 pk;
            #pragma unroll
            for (int r = 0; r < 4; ++r) {
                float sv = sc[r] * SCALE + bf2f(((const short*)&b4[nt])[r]);
                float pv = kvalid ? __expf(sv) : 0.f;
                sacc += pv;
                ((short*)&pk)[r] = f2bf(pv);
            }
            *(short4*)(Psw + lr * 128 + ((nt * 32 + kg * 8) ^ swz)) = pk;
        }
        // PV
        #pragma unroll
        for (int ks = 0; ks < 2; ++ks) {
            bf16x8 pa = *(const bf16x8*)(Psw + lr * 128 + ((ks * 64 + kg * 16) ^ swz));
            #pragma unroll
            for (int nt = 0; nt < 4; ++nt)
                acc[nt] = MFMA32(pa, vf[ks * 4 + nt], acc[nt]);
        }
    };

    LOADKB(0, kaA, b4A);
    for (int tile = 0; tile < 12; tile += 2) {
        COMPUTE(tile,     kaA, b4A, tile + 1, kaB, b4B);
        COMPUTE(tile + 1, kaB, b4B, tile + 2, kaA, b4A);
    }
    COMPUTE(12, kaA, b4A, -1, kaB, b4B);

    sacc += __shfl_xor(sacc, 16, 64);
    sacc += __shfl_xor(sacc, 32, 64);

    #pragma unroll
    for (int r = 0; r < 4; ++r) {
        int qrow_ = qt * 64 + wid * 16 + kg * 4 + r;
        if (qrow_ >= NN2) continue;
        float inv = 1.f / __shfl(sacc, kg * 4 + r, 64);
        #pragma unroll
        for (int nt = 0; nt < 4; ++nt) {
            int d = nt * 16 + lr;
            outT[((size_t)b * NN2 + qrow_) * DH + h * DD + d] = acc[nt][r] * inv;
        }
    }
}

// ---------------- gelu(attnT + vlocal^T) -> gT hi/lo [b][256][512] ----------------
__global__ void gelu_addT_kernel(const float* __restrict__ aT, const float* __restrict__ vloc,
                                 short* __restrict__ g_hi, short* __restrict__ g_lo) {
    __shared__ float tile[32][33];
    int ntb = blockIdx.x * 32, ctb = blockIdx.y * 32, b = blockIdx.z;
    int tn = threadIdx.x & 31, tc4 = threadIdx.x >> 5;
    #pragma unroll
    for (int i = 0; i < 4; ++i) {
        int c = tc4 + i * 8;
        int n = ntb + tn;
        tile[c][tn] = (n < NN2) ? vloc[((size_t)b * DH + ctb + c) * NN2 + n] : 0.f;
    }
    __syncthreads();
    int tc = threadIdx.x & 31, tn4 = threadIdx.x >> 5;
    #pragma unroll
    for (int i = 0; i < 4; ++i) {
        int n = ntb + tn4 + i * 8;
        float g = 0.f;
        if (n < NN2) {
            float sum = aT[((size_t)b * NN2 + n) * DH + ctb + tc] + tile[tc][tn4 + i * 8];
            g = 0.5f * sum * (1.f + erff(sum * 0.70710678118654752440f));
        }
        short hh = f2bf(g);
        size_t o = ((size_t)b * QPAD + n) * DH + ctb + tc;
        g_hi[o] = hh;
        g_lo[o] = f2bf(g - bf2f(hh));
    }
}

extern "C" void kernel_launch(void* const* d_in, const int* in_sizes, int n_in,
                              void* d_out, int out_size, void* d_ws, size_t ws_size,
                              hipStream_t stream) {
    const float* x     = (const float*)d_in[0];
    const float* ql_w  = (const float*)d_in[1];
    const float* ql_b  = (const float*)d_in[2];
    const float* qp_w  = (const float*)d_in[3];
    const float* qp_b  = (const float*)d_in[4];
    const float* qp_s  = (const float*)d_in[5];
    const float* qp_o  = (const float*)d_in[6];
    const float* k_w   = (const float*)d_in[7];
    const float* k_b   = (const float*)d_in[8];
    const float* k_s   = (const float*)d_in[9];
    const float* k_o   = (const float*)d_in[10];
    const float* v_w   = (const float*)d_in[11];
    const float* v_b   = (const float*)d_in[12];
    const float* v_s   = (const float*)d_in[13];
    const float* v_o   = (const float*)d_in[14];
    const float* vl_w  = (const float*)d_in[15];
    const float* vl_b  = (const float*)d_in[16];
    const float* vl_s  = (const float*)d_in[17];
    const float* vl_o  = (const float*)d_in[18];
    const float* p_w   = (const float*)d_in[19];
    const float* p_b   = (const float*)d_in[20];
    const float* p_s   = (const float*)d_in[21];
    const float* p_o   = (const float*)d_in[22];
    const float* ab    = (const float*)d_in[23];
    const int*   bidx  = (const int*)d_in[24];
    float* out = (float*)d_out;
    int n_off = in_sizes[23] / HEADS;

    char* ws = (char*)d_ws;
    float* qin    = (float*)(ws + O_QIN);
    short* qinT_h = (short*)(ws + O_QINT_HI);
    short* xT_h   = (short*)(ws + O_XT_HI);
    short* QT     = (short*)(ws + O_QT);
    short* KT     = (short*)(ws + O_KT);
    short* Vb     = (short*)(ws + O_V);
    float* vlocal = (float*)(ws + O_VLOCAL);
    short* biasB  = (short*)(ws + O_BIASB);
    short* w_h    = (short*)(ws + O_W_HI);
    short* w_l    = (short*)(ws + O_W_LO);
    float* attnT  = (float*)(ws + O_ATTNT);
    short* gT_h   = (short*)(ws + O_GT_HI);
    short* gT_l   = (short*)(ws + O_GT_LO);

    // 1. qin (fp32)
    qin_kernel<<<dim3(DIMC, BATCH), 256, 0, stream>>>(x, ql_w, ql_b, qin);
    // 2. weight splits
    wsplit_kernel<<<dim3(1920), 256, 0, stream>>>(qp_w, k_w, v_w, p_w, w_h, w_l);
    // 3. qin -> qinT (bf16 hi only)
    tsplit_kernel<<<dim3(QPAD / 32, DIMC / 32, BATCH), 256, 0, stream>>>(qin, qinT_h, DIMC, NN2, QPAD);
    // 4. q projection -> QT packed
    gemm_split_kernel<false><<<dim3(2, 1, BATCH), 256, 0, stream>>>(
        w_h + 0, w_l + 0, qinT_h, nullptr, qp_b, qp_s, qp_o,
        nullptr, QT, 2, DIMC, NN2, QPAD, QPAD);
    // 5. x -> xT (bf16 hi only)
    tsplit_kernel<<<dim3(XPAD / 32, DIMC / 32, BATCH), 256, 0, stream>>>(x, xT_h, DIMC, NN, XPAD);
    // 6. k projection -> KT packed
    gemm_split_kernel<false><<<dim3(7, 1, BATCH), 256, 0, stream>>>(
        w_h + 49152, w_l + 49152, xT_h, nullptr, k_b, k_s, k_o,
        nullptr, KT, 2, DIMC, NN, XPAD, KPAD);
    // 7. v projection -> bf16 [b][512][832]
    gemm_split_kernel<false><<<dim3(7, 4, BATCH), 256, 0, stream>>>(
        w_h + 98304, w_l + 98304, xT_h, nullptr, v_b, v_s, v_o,
        nullptr, Vb, 1, DIMC, NN, XPAD, KPAD);
    // 8. v_local
    vlocal_kernel<<<dim3(DH, BATCH), 256, 0, stream>>>(Vb, vl_w, vl_b, vl_s, vl_o, vlocal);
    // 9. bias expand
    biasB_expand_kernel<<<dim3((NN2 * KPAD + 255) / 256, HEADS), 256, 0, stream>>>(ab, bidx, biasB, n_off);
    // 10. attention (register-pipelined, zero barriers)
    attn_mfma5_kernel<<<dim3(4 * HEADS * BATCH), 256, 0, stream>>>(QT, KT, Vb, biasB, attnT);
    // 11. gelu
    gelu_addT_kernel<<<dim3(QPAD / 32, DH / 32, BATCH), 256, 0, stream>>>(attnT, vlocal, gT_h, gT_l);
    // 12. output projection (keeps B-lo split)
    gemm_split_kernel<true><<<dim3(2, 3, BATCH), 256, 0, stream>>>(
        w_h + 294912, w_l + 294912, gT_h, gT_l, p_b, p_s, p_o,
        out, nullptr, 0, DH, NN2, QPAD, 0);
}